// Round 1
// baseline (227.157 us; speedup 1.0000x reference)
//
#include <hip/hip_runtime.h>

// LIF recurrence over the last (time) dim, T = 8, fp32 in/out.
//   u_t = TAU * u_{t-1} * (1 - o_{t-1}) + x_t
//   o_t = (u_t - VTH > 0) ? 1 : 0
// One thread per neuron: 8 contiguous floats in, 8 contiguous floats out.
// Memory-bound: 268 MB total traffic -> ~43 us floor at 6.3 TB/s.

#define LIF_TAU 0.25f
#define LIF_VTH 0.3f

__global__ __launch_bounds__(256) void lif_spike_kernel(
    const float* __restrict__ x, float* __restrict__ out, int n_neurons) {
    int tid = blockIdx.x * blockDim.x + threadIdx.x;
    if (tid >= n_neurons) return;

    const float4* xv = reinterpret_cast<const float4*>(x) + (size_t)tid * 2;
    float4 a = xv[0];
    float4 b = xv[1];
    float xs[8] = {a.x, a.y, a.z, a.w, b.x, b.y, b.z, b.w};

    float u = 0.0f;
    float o = 0.0f;
    float os[8];
#pragma unroll
    for (int t = 0; t < 8; ++t) {
        u = LIF_TAU * u * (1.0f - o) + xs[t];
        o = (u > LIF_VTH) ? 1.0f : 0.0f;
        os[t] = o;
    }

    float4* ov = reinterpret_cast<float4*>(out) + (size_t)tid * 2;
    ov[0] = make_float4(os[0], os[1], os[2], os[3]);
    ov[1] = make_float4(os[4], os[5], os[6], os[7]);
}

extern "C" void kernel_launch(void* const* d_in, const int* in_sizes, int n_in,
                              void* d_out, int out_size, void* d_ws, size_t ws_size,
                              hipStream_t stream) {
    const float* x = (const float*)d_in[0];
    float* out = (float*)d_out;
    int n_elems = in_sizes[0];          // 33,554,432
    int n_neurons = n_elems / 8;        // 4,194,304 (T = 8)

    int block = 256;
    int grid = (n_neurons + block - 1) / block;
    lif_spike_kernel<<<grid, block, 0, stream>>>(x, out, n_neurons);
}

// Round 2
// 217.340 us; speedup vs baseline: 1.0452x; 1.0452x over previous
//
#include <hip/hip_runtime.h>

// LIF recurrence over last (time) dim, T=8, fp32 in/out. 4,194,304 neurons.
//   u_t = TAU * u_{t-1} * (1 - o_{t-1}) + x_t ;  o_t = (u_t > VTH) ? 1 : 0
//
// Memory-bound: 134 MB read + 134 MB write -> ~43 us floor at 6.3 TB/s.
// This version stages through LDS (time-major, pitch 257) so every global
// load/store is unit-stride float4 per lane (16 B/lane). All LDS access
// patterns are exactly 2-way bank-aliased (free on CDNA4 [m136]).

#define LIF_TAU 0.25f
#define LIF_VTH 0.3f
#define T_STEPS 8
#define BLOCK 256
#define ROW 257   // LDS row pitch in dwords; 257 % 32 == 1 -> conflict-free patterns

typedef float v4f __attribute__((ext_vector_type(4)));

__global__ __launch_bounds__(BLOCK) void lif_spike_kernel(
    const float* __restrict__ x, float* __restrict__ out) {
    __shared__ float lds[T_STEPS * ROW];

    const int t = threadIdx.x;
    // Each block owns 256 neurons = 2048 contiguous floats = 512 float4.
    const size_t blk4 = (size_t)blockIdx.x * (BLOCK * T_STEPS / 4);
    const v4f* __restrict__ xv = reinterpret_cast<const v4f*>(x) + blk4;
    v4f* __restrict__ ov = reinterpret_cast<v4f*>(out) + blk4;

    // ---- Phase 1: unit-stride global load, transpose into LDS ----
    v4f v0 = __builtin_nontemporal_load(xv + t);           // floats [4t, 4t+3]
    v4f v1 = __builtin_nontemporal_load(xv + t + BLOCK);   // floats [1024+4t, ...]

    // float l = 4t+k  ->  neuron t/2, time (t&1)*4 + k  (neurons 0..127)
    // v1: same but neuron += 128
    const int n0 = t >> 1;
    const int tb = (t & 1) * 4;
    lds[(tb + 0) * ROW + n0] = v0.x;
    lds[(tb + 1) * ROW + n0] = v0.y;
    lds[(tb + 2) * ROW + n0] = v0.z;
    lds[(tb + 3) * ROW + n0] = v0.w;
    lds[(tb + 0) * ROW + n0 + 128] = v1.x;
    lds[(tb + 1) * ROW + n0 + 128] = v1.y;
    lds[(tb + 2) * ROW + n0 + 128] = v1.z;
    lds[(tb + 3) * ROW + n0 + 128] = v1.w;
    __syncthreads();

    // ---- Phase 2: per-neuron recurrence, thread t owns neuron t ----
    float u = 0.0f, o = 0.0f;
#pragma unroll
    for (int k = 0; k < T_STEPS; ++k) {
        float xk = lds[k * ROW + t];
        u = LIF_TAU * u * (1.0f - o) + xk;
        o = (u > LIF_VTH) ? 1.0f : 0.0f;
        lds[k * ROW + t] = o;   // in-place: slot owned by this thread only
    }
    __syncthreads();

    // ---- Phase 3: gather from LDS, unit-stride nontemporal global store ----
    v4f w0, w1;
    w0.x = lds[(tb + 0) * ROW + n0];
    w0.y = lds[(tb + 1) * ROW + n0];
    w0.z = lds[(tb + 2) * ROW + n0];
    w0.w = lds[(tb + 3) * ROW + n0];
    w1.x = lds[(tb + 0) * ROW + n0 + 128];
    w1.y = lds[(tb + 1) * ROW + n0 + 128];
    w1.z = lds[(tb + 2) * ROW + n0 + 128];
    w1.w = lds[(tb + 3) * ROW + n0 + 128];
    __builtin_nontemporal_store(w0, ov + t);
    __builtin_nontemporal_store(w1, ov + t + BLOCK);
}

extern "C" void kernel_launch(void* const* d_in, const int* in_sizes, int n_in,
                              void* d_out, int out_size, void* d_ws, size_t ws_size,
                              hipStream_t stream) {
    const float* x = (const float*)d_in[0];
    float* out = (float*)d_out;
    int n_elems = in_sizes[0];                    // 33,554,432 (divisible by 2048)
    int n_blocks = n_elems / (BLOCK * T_STEPS);   // 16384

    lif_spike_kernel<<<n_blocks, BLOCK, 0, stream>>>(x, out);
}

// Round 3
// 215.956 us; speedup vs baseline: 1.0519x; 1.0064x over previous
//
#include <hip/hip_runtime.h>

// LIF recurrence over last (time) dim, T=8, fp32 in/out. 4,194,304 neurons.
//   u_t = TAU * u_{t-1} * (1 - o_{t-1}) + x_t ;  o_t = (u_t > VTH) ? 1 : 0
//
// Memory-bound: 134 MB read + 134 MB write -> ~43 us floor at ~6.3 TB/s.
// Unit-stride float4 load/store per lane; the neuron's two time-halves live
// in adjacent lanes (pair 2n/2n+1 of the same wave), so the recurrence carry
// is exchanged in-register via __shfl_xor(1) -- no LDS, no barriers.
//   pass 1: all lanes run their 4 steps from (u,o)=(0,0)   (valid for even lanes)
//   xchg  : odd lanes take partner's (u,o) as carry; even lanes take (0,0)
//   pass 2: all lanes re-run their 4 steps with the correct carry and emit spikes

#define LIF_TAU 0.25f
#define LIF_VTH 0.3f
#define BLOCK 256

typedef float v4f __attribute__((ext_vector_type(4)));

__global__ __launch_bounds__(BLOCK) void lif_spike_kernel(
    const float* __restrict__ x, float* __restrict__ out) {
    const size_t g = (size_t)blockIdx.x * BLOCK + threadIdx.x;

    const v4f* __restrict__ xv = reinterpret_cast<const v4f*>(x);
    v4f* __restrict__ ov = reinterpret_cast<v4f*>(out);

    v4f v = __builtin_nontemporal_load(xv + g);   // floats [4g .. 4g+3]

    // pass 1: speculative 4 steps from (0,0)
    float u = 0.0f, o = 0.0f;
#pragma unroll
    for (int k = 0; k < 4; ++k) {
        u = LIF_TAU * u * (1.0f - o) + v[k];
        o = (u > LIF_VTH) ? 1.0f : 0.0f;
    }

    // carry exchange with pair partner (adjacent lane, same wave)
    float cu = __shfl_xor(u, 1);
    float co = __shfl_xor(o, 1);
    const bool odd = (threadIdx.x & 1) != 0;
    u = odd ? cu : 0.0f;
    o = odd ? co : 0.0f;

    // pass 2: definitive 4 steps (even lanes recompute identical values)
    v4f w;
#pragma unroll
    for (int k = 0; k < 4; ++k) {
        u = LIF_TAU * u * (1.0f - o) + v[k];
        o = (u > LIF_VTH) ? 1.0f : 0.0f;
        w[k] = o;
    }

    __builtin_nontemporal_store(w, ov + g);
}

extern "C" void kernel_launch(void* const* d_in, const int* in_sizes, int n_in,
                              void* d_out, int out_size, void* d_ws, size_t ws_size,
                              hipStream_t stream) {
    const float* x = (const float*)d_in[0];
    float* out = (float*)d_out;
    int n_elems = in_sizes[0];        // 33,554,432
    int n_vec4 = n_elems / 4;         // 8,388,608 float4s, one per thread
    int n_blocks = n_vec4 / BLOCK;    // 32768

    lif_spike_kernel<<<n_blocks, BLOCK, 0, stream>>>(x, out);
}